// Round 3
// baseline (752.519 us; speedup 1.0000x reference)
//
#include <hip/hip_runtime.h>

#define NN 50000
#define NE 800000
#define DIN 128
#define HD 128
#define CD 64

// ---------------- degree / dinv ----------------
__global__ void init_deg(float* __restrict__ degf) {
    int i = blockIdx.x * blockDim.x + threadIdx.x;
    if (i < NN) degf[i] = 2.0f;  // two self loops
}

__global__ void count_deg(const int* __restrict__ dst, float* __restrict__ degf) {
    int e = blockIdx.x * blockDim.x + threadIdx.x;
    if (e < NE) atomicAdd(&degf[dst[e]], 1.0f);
}

__global__ void make_dinv(float* __restrict__ degf) {
    int i = blockIdx.x * blockDim.x + threadIdx.x;
    if (i < NN) degf[i] = rsqrtf(degf[i]);
}

// ---------------- GEMM1: hs1[v,j] = dinv[v] * sum_k x[v,k] * W1[k,j] ----------------
// 256 threads = 2 rows x 128 cols per block
__global__ void gemm1(const float* __restrict__ x, const float* __restrict__ W1,
                      const float* __restrict__ dinv, float* __restrict__ hs1) {
    __shared__ float xs[2][DIN];
    int t = threadIdx.x;
    int r = t / DIN, c = t % DIN;
    int row0 = blockIdx.x * 2;
    xs[r][c] = x[(long)(row0 + r) * DIN + c];
    __syncthreads();
    int row = row0 + r;
    float acc = 0.f;
#pragma unroll 8
    for (int k = 0; k < DIN; ++k)
        acc += xs[r][k] * W1[k * HD + c];
    hs1[(long)row * HD + c] = acc * dinv[row];
}

// ---------------- GEMM2: hs2[v,c] = dinv[v] * sum_k h1[v,k] * W2[k,c] ----------------
// 256 threads = 4 rows x 64 cols per block
__global__ void gemm2(const float* __restrict__ h1, const float* __restrict__ W2,
                      const float* __restrict__ dinv, float* __restrict__ hs2) {
    __shared__ float xs[4][DIN];
    int t = threadIdx.x;
    int row0 = blockIdx.x * 4;
    for (int i = t; i < 4 * DIN; i += 256)
        xs[i / DIN][i % DIN] = h1[(long)(row0 + i / DIN) * DIN + (i % DIN)];
    __syncthreads();
    int r = t / CD, c = t % CD;
    int row = row0 + r;
    float acc = 0.f;
#pragma unroll 8
    for (int k = 0; k < DIN; ++k)
        acc += xs[r][k] * W2[k * CD + c];
    hs2[(long)row * CD + c] = acc * dinv[row];
}

// ---------------- edge scatter: agg[dst] += hs[src] ----------------
// layer1: 2 edges x 128 cols per 256-thread block
__global__ void scatter1(const int* __restrict__ src, const int* __restrict__ dst,
                         const float* __restrict__ hs1, float* __restrict__ agg1) {
    int t = threadIdx.x;
    long e = (long)blockIdx.x * 2 + (t >> 7);
    int c = t & 127;
    int s = src[e], d = dst[e];
    atomicAdd(&agg1[(long)d * HD + c], hs1[(long)s * HD + c]);
}

// layer2: 4 edges x 64 cols per 256-thread block
__global__ void scatter2(const int* __restrict__ src, const int* __restrict__ dst,
                         const float* __restrict__ hs2, float* __restrict__ agg2) {
    int t = threadIdx.x;
    long e = (long)blockIdx.x * 4 + (t >> 6);
    int c = t & 63;
    int s = src[e], d = dst[e];
    atomicAdd(&agg2[(long)d * CD + c], hs2[(long)s * CD + c]);
}

// ---------------- finalize1: h1 = relu(dinv*(agg + 2*hs) + b1), in place into agg1 ----------------
__global__ void finalize1(float* __restrict__ agg1, const float* __restrict__ hs1,
                          const float* __restrict__ dinv, const float* __restrict__ b1) {
    long i = (long)blockIdx.x * blockDim.x + threadIdx.x;
    if (i < (long)NN * HD) {
        int v = (int)(i / HD), j = (int)(i % HD);
        float o = dinv[v] * (agg1[i] + 2.f * hs1[i]) + b1[j];
        agg1[i] = fmaxf(o, 0.f);
    }
}

// ---------------- finalize2 + log_softmax: one 64-lane wave per row ----------------
__global__ void finalize2(const float* __restrict__ agg2, const float* __restrict__ hs2,
                          const float* __restrict__ dinv, const float* __restrict__ b2,
                          float* __restrict__ out) {
    int t = threadIdx.x;
    int row = blockIdx.x * 4 + (t >> 6);
    int c = t & 63;
    long i = (long)row * CD + c;
    float o = dinv[row] * (agg2[i] + 2.f * hs2[i]) + b2[c];
    float m = o;
#pragma unroll
    for (int off = 32; off >= 1; off >>= 1) m = fmaxf(m, __shfl_xor(m, off, 64));
    float ex = __expf(o - m);
    float s = ex;
#pragma unroll
    for (int off = 32; off >= 1; off >>= 1) s += __shfl_xor(s, off, 64);
    out[i] = o - m - __logf(s);
}

extern "C" void kernel_launch(void* const* d_in, const int* in_sizes, int n_in,
                              void* d_out, int out_size, void* d_ws, size_t ws_size,
                              hipStream_t stream) {
    const float* x  = (const float*)d_in[0];
    const int*   ei = (const int*)d_in[1];   // [2, E] int32
    const float* W1 = (const float*)d_in[2];
    const float* b1 = (const float*)d_in[3];
    const float* W2 = (const float*)d_in[4];
    const float* b2 = (const float*)d_in[5];
    float* out = (float*)d_out;

    const int* src = ei;
    const int* dst = ei + NE;

    float* ws = (float*)d_ws;
    float* dinv = ws;                         // NN floats (degf then dinv, in place)
    float* hs1  = ws + 51200;                 // NN*HD floats
    float* agg1 = hs1 + (long)NN * HD;        // NN*HD floats (becomes h1 after finalize1)
    float* hs2  = hs1;                        // NN*CD floats (reuse)
    float* agg2 = hs1 + (long)NN * CD;        // NN*CD floats (reuse)

    // degrees
    init_deg<<<(NN + 255) / 256, 256, 0, stream>>>(dinv);
    count_deg<<<(NE + 255) / 256, 256, 0, stream>>>(dst, dinv);
    make_dinv<<<(NN + 255) / 256, 256, 0, stream>>>(dinv);

    // layer 1
    hipMemsetAsync(agg1, 0, (size_t)NN * HD * sizeof(float), stream);
    gemm1<<<NN / 2, 256, 0, stream>>>(x, W1, dinv, hs1);
    scatter1<<<NE / 2, 256, 0, stream>>>(src, dst, hs1, agg1);
    finalize1<<<((long)NN * HD + 255) / 256, 256, 0, stream>>>(agg1, hs1, dinv, b1);

    // layer 2 (h1 lives in agg1; hs2/agg2 reuse the hs1 region)
    hipMemsetAsync(agg2, 0, (size_t)NN * CD * sizeof(float), stream);
    gemm2<<<NN / 4, 256, 0, stream>>>(agg1, W2, dinv, hs2);
    scatter2<<<NE / 4, 256, 0, stream>>>(src, dst, hs2, agg2);
    finalize2<<<NN / 4, 256, 0, stream>>>(agg2, hs2, dinv, b2, out);
}

// Round 4
// 551.843 us; speedup vs baseline: 1.3636x; 1.3636x over previous
//
#include <hip/hip_runtime.h>

#define NN 50000
#define NE 800000
#define DIN 128
#define HD 128
#define CD 64

// ---------------- CSR build ----------------
__global__ void zero_cnt(int* __restrict__ cnt) {
    int i = blockIdx.x * blockDim.x + threadIdx.x;
    if (i < NN) cnt[i] = 0;
}

__global__ void count_deg(const int* __restrict__ dst, int* __restrict__ cnt) {
    int e = blockIdx.x * blockDim.x + threadIdx.x;
    if (e < NE) atomicAdd(&cnt[dst[e]], 1);
}

__global__ void dinv_from_cnt(const int* __restrict__ cnt, float* __restrict__ dinv) {
    int i = blockIdx.x * blockDim.x + threadIdx.x;
    if (i < NN) dinv[i] = rsqrtf((float)(cnt[i] + 2));  // +2 self loops
}

// single-block exclusive scan over NN elements, in place (counts -> start offsets)
__global__ void __launch_bounds__(1024) scan_cnt(int* __restrict__ cnt) {
    __shared__ int lds[1024];
    __shared__ int carry_s;
    int t = threadIdx.x;
    if (t == 0) carry_s = 0;
    __syncthreads();
    for (int base = 0; base < NN; base += 1024) {
        int i = base + t;
        int v = (i < NN) ? cnt[i] : 0;
        lds[t] = v;
        __syncthreads();
        for (int off = 1; off < 1024; off <<= 1) {
            int a = (t >= off) ? lds[t - off] : 0;
            __syncthreads();
            lds[t] += a;
            __syncthreads();
        }
        int incl = lds[t];
        int c = carry_s;
        if (i < NN) cnt[i] = c + incl - v;  // exclusive
        __syncthreads();
        if (t == 1023) carry_s = c + lds[1023];  // lds[1023] == chunk total
        __syncthreads();
    }
}

// fill: after this, rowptr[v] == end offset of v (== start of v+1)
__global__ void fill_csr(const int* __restrict__ src, const int* __restrict__ dst,
                         int* __restrict__ rowptr, int* __restrict__ col) {
    int e = blockIdx.x * blockDim.x + threadIdx.x;
    if (e < NE) {
        int d = dst[e];
        int pos = atomicAdd(&rowptr[d], 1);
        col[pos] = src[e];
    }
}

// ---------------- GEMM1: hs1[v,j] = dinv[v] * sum_k x[v,k] * W1[k,j] ----------------
__global__ void gemm1(const float* __restrict__ x, const float* __restrict__ W1,
                      const float* __restrict__ dinv, float* __restrict__ hs1) {
    __shared__ float xs[2][DIN];
    int t = threadIdx.x;
    int r = t / DIN, c = t % DIN;
    int row0 = blockIdx.x * 2;
    xs[r][c] = x[(long)(row0 + r) * DIN + c];
    __syncthreads();
    int row = row0 + r;
    float acc = 0.f;
#pragma unroll 8
    for (int k = 0; k < DIN; ++k)
        acc += xs[r][k] * W1[k * HD + c];
    hs1[(long)row * HD + c] = acc * dinv[row];
}

// ---------------- GEMM2: hs2[v,c] = dinv[v] * sum_k h1[v,k] * W2[k,c] ----------------
__global__ void gemm2(const float* __restrict__ h1, const float* __restrict__ W2,
                      const float* __restrict__ dinv, float* __restrict__ hs2) {
    __shared__ float xs[4][DIN];
    int t = threadIdx.x;
    int row0 = blockIdx.x * 4;
    for (int i = t; i < 4 * DIN; i += 256)
        xs[i / DIN][i % DIN] = h1[(long)(row0 + i / DIN) * DIN + (i % DIN)];
    __syncthreads();
    int r = t / CD, c = t % CD;
    int row = row0 + r;
    float acc = 0.f;
#pragma unroll 8
    for (int k = 0; k < DIN; ++k)
        acc += xs[r][k] * W2[k * CD + c];
    hs2[(long)row * CD + c] = acc * dinv[row];
}

// ---------------- agg1 (CSR gather) + finalize1 + relu, fused ----------------
// 256 threads = 2 dst rows x 128 cols
__global__ void agg1_csr(const int* __restrict__ rowptr, const int* __restrict__ col,
                         const float* __restrict__ hs1, const float* __restrict__ dinv,
                         const float* __restrict__ b1, float* __restrict__ h1) {
    int t = threadIdx.x;
    int v = blockIdx.x * 2 + (t >> 7);
    int c = t & 127;
    int start = (v == 0) ? 0 : rowptr[v - 1];
    int end = rowptr[v];
    float acc = 2.f * hs1[(long)v * HD + c];  // two self loops
    for (int j = start; j < end; ++j) {
        int s = col[j];  // uniform across the wave -> broadcast
        acc += hs1[(long)s * HD + c];
    }
    float o = dinv[v] * acc + b1[c];
    h1[(long)v * HD + c] = fmaxf(o, 0.f);
}

// ---------------- agg2 (CSR gather) + finalize2 + log_softmax, fused ----------------
// 256 threads = 4 dst rows x 64 cols (one wave per row)
__global__ void agg2_csr(const int* __restrict__ rowptr, const int* __restrict__ col,
                         const float* __restrict__ hs2, const float* __restrict__ dinv,
                         const float* __restrict__ b2, float* __restrict__ out) {
    int t = threadIdx.x;
    int v = blockIdx.x * 4 + (t >> 6);
    int c = t & 63;
    int start = (v == 0) ? 0 : rowptr[v - 1];
    int end = rowptr[v];
    float acc = 2.f * hs2[(long)v * CD + c];
    for (int j = start; j < end; ++j) {
        int s = col[j];
        acc += hs2[(long)s * CD + c];
    }
    float o = dinv[v] * acc + b2[c];
    float m = o;
#pragma unroll
    for (int off = 32; off >= 1; off >>= 1) m = fmaxf(m, __shfl_xor(m, off, 64));
    float ex = __expf(o - m);
    float s = ex;
#pragma unroll
    for (int off = 32; off >= 1; off >>= 1) s += __shfl_xor(s, off, 64);
    out[(long)v * CD + c] = o - m - __logf(s);
}

extern "C" void kernel_launch(void* const* d_in, const int* in_sizes, int n_in,
                              void* d_out, int out_size, void* d_ws, size_t ws_size,
                              hipStream_t stream) {
    const float* x  = (const float*)d_in[0];
    const int*   ei = (const int*)d_in[1];   // [2, E] int32
    const float* W1 = (const float*)d_in[2];
    const float* b1 = (const float*)d_in[3];
    const float* W2 = (const float*)d_in[4];
    const float* b2 = (const float*)d_in[5];
    float* out = (float*)d_out;

    const int* src = ei;
    const int* dst = ei + NE;

    float* ws = (float*)d_ws;
    // layout (float-index offsets):
    float* dinv   = ws;                        // [0, 65536)
    int*   rowptr = (int*)(ws + 65536);        // [65536, 131072)  NN ints
    int*   col    = (int*)(ws + 131072);       // NE ints -> next free at 933888
    float* hs1    = ws + 933888;               // NN*HD = 6.4M floats
    float* h1     = ws + 7333888;              // NN*HD
    float* hs2    = hs1;                       // reuse (hs1 dead after agg1)

    // ---- CSR build (amortized over both layers) ----
    zero_cnt<<<(NN + 255) / 256, 256, 0, stream>>>(rowptr);
    count_deg<<<(NE + 255) / 256, 256, 0, stream>>>(dst, rowptr);
    dinv_from_cnt<<<(NN + 255) / 256, 256, 0, stream>>>(rowptr, dinv);
    scan_cnt<<<1, 1024, 0, stream>>>(rowptr);
    fill_csr<<<(NE + 255) / 256, 256, 0, stream>>>(src, dst, rowptr, col);

    // ---- layer 1 ----
    gemm1<<<NN / 2, 256, 0, stream>>>(x, W1, dinv, hs1);
    agg1_csr<<<NN / 2, 256, 0, stream>>>(rowptr, col, hs1, dinv, b1, h1);

    // ---- layer 2 ----
    gemm2<<<NN / 4, 256, 0, stream>>>(h1, W2, dinv, hs2);
    agg2_csr<<<NN / 4, 256, 0, stream>>>(rowptr, col, hs2, dinv, b2, out);
}